// Round 1
// baseline (480.982 us; speedup 1.0000x reference)
//
#include <hip/hip_runtime.h>

typedef __attribute__((ext_vector_type(8))) short short8;
typedef __attribute__((ext_vector_type(4))) float f32x4;
typedef __attribute__((ext_vector_type(4))) unsigned short us4;
typedef __attribute__((ext_vector_type(4))) float float4v;

#define GLB_PTR(p) ((const __attribute__((address_space(1))) void*)(p))
#define LDS_PTR(p) ((__attribute__((address_space(3))) void*)(p))

__device__ __forceinline__ unsigned short f2bf(float f) {
  unsigned int u = __float_as_uint(f);
  u += 0x7FFF + ((u >> 16) & 1);   // round-to-nearest-even
  return (unsigned short)(u >> 16);
}

// ---------------- fp32 -> bf16 convert (vectorized) ----------------
__global__ void cvt_kernel(const float* __restrict__ in, unsigned short* __restrict__ out, int n4) {
  int i = blockIdx.x * blockDim.x + threadIdx.x;
  int stride = gridDim.x * blockDim.x;
  for (; i < n4; i += stride) {
    float4v v = *(const float4v*)(in + (size_t)i * 4);
    us4 o;
    o[0] = f2bf(v[0]); o[1] = f2bf(v[1]); o[2] = f2bf(v[2]); o[3] = f2bf(v[3]);
    *(us4*)(out + (size_t)i * 4) = o;
  }
}

// ---------------- bf16 GEMM: C[M,N] = A[M,K] * B[N,K]^T ----------------
// MODE 0: C as bf16.  MODE 1: C fp32 = acc + bias[n] + resid[m,n].
template<int MODE>
__global__ __launch_bounds__(256) void gemm_bt(
    const unsigned short* __restrict__ A,
    const unsigned short* __restrict__ B,
    unsigned short* __restrict__ Cb,
    float* __restrict__ Cf,
    const float* __restrict__ bias,
    const float* __restrict__ resid,
    int K, int N, int Mc /* clamp for A row reads */) {
  __shared__ unsigned short As[128 * 32];
  __shared__ unsigned short Bs[128 * 32];
  const int m0 = blockIdx.x * 128, n0 = blockIdx.y * 128;
  const int t = threadIdx.x;
  const int w = t >> 6, l = t & 63, lr = l & 15, lg = l >> 4;
  const int wr = w >> 1, wc = w & 1;
  const int srow = t >> 2, scol = (t & 3) * 8;

  f32x4 acc[4][4] = {};
  unsigned short* AsW = As + w * 512;  // wave-uniform LDS base (bytes: w*1024)
  unsigned short* BsW = Bs + w * 512;

  for (int k0 = 0; k0 < K; k0 += 32) {
    long ar0 = m0 + srow;       if (ar0 > Mc) ar0 = Mc;
    long ar1 = m0 + srow + 64;  if (ar1 > Mc) ar1 = Mc;
    __builtin_amdgcn_global_load_lds(GLB_PTR(A + ar0 * (long)K + k0 + scol), LDS_PTR(AsW),        16, 0, 0);
    __builtin_amdgcn_global_load_lds(GLB_PTR(A + ar1 * (long)K + k0 + scol), LDS_PTR(AsW + 2048), 16, 0, 0);
    __builtin_amdgcn_global_load_lds(GLB_PTR(B + (long)(n0 + srow) * K + k0 + scol),      LDS_PTR(BsW),        16, 0, 0);
    __builtin_amdgcn_global_load_lds(GLB_PTR(B + (long)(n0 + srow + 64) * K + k0 + scol), LDS_PTR(BsW + 2048), 16, 0, 0);
    __syncthreads();

    short8 af[4], bfv[4];
#pragma unroll
    for (int i = 0; i < 4; ++i) {
      af[i]  = *(const short8*)(As + (wr * 64 + i * 16 + lr) * 32 + lg * 8);
      bfv[i] = *(const short8*)(Bs + (wc * 64 + i * 16 + lr) * 32 + lg * 8);
    }
#pragma unroll
    for (int i = 0; i < 4; ++i)
#pragma unroll
      for (int j = 0; j < 4; ++j)
        acc[i][j] = __builtin_amdgcn_mfma_f32_16x16x32_bf16(af[i], bfv[j], acc[i][j], 0, 0, 0);
    __syncthreads();
  }

#pragma unroll
  for (int i = 0; i < 4; ++i) {
    int rb = m0 + wr * 64 + i * 16 + lg * 4;
#pragma unroll
    for (int j = 0; j < 4; ++j) {
      int col = n0 + wc * 64 + j * 16 + lr;
#pragma unroll
      for (int r = 0; r < 4; ++r) {
        long row = rb + r;
        if (MODE == 0) {
          Cb[row * (long)N + col] = f2bf(acc[i][j][r]);
        } else {
          Cf[row * (long)N + col] = acc[i][j][r] + bias[col] + resid[row * (long)N + col];
        }
      }
    }
  }
}

// ---------------- V transpose: Vb[(c*154+e), h*64+d] -> Vt[c][h][d][e(160, zero-pad)] ----------------
__global__ void vtrans(const unsigned short* __restrict__ Vb, unsigned short* __restrict__ Vt) {
  int c = blockIdx.x / 24, h = blockIdx.x % 24;
  for (int idx = threadIdx.x; idx < 64 * 160; idx += blockDim.x) {
    int d = idx & 63, e = idx >> 6;
    unsigned short v = 0;
    if (e < 154) v = Vb[(long)(c * 154 + e) * 1536 + h * 64 + d];
    Vt[((long)((c * 24 + h) * 64 + d)) * 160 + e] = v;
  }
}

// ---------------- fused cross-component attention ----------------
// grid (64 s-blocks, 24 heads), 256 threads = 4 waves; wave owns 16 s-rows, all 4 components.
__global__ __launch_bounds__(256) void attn_kernel(
    const unsigned short* __restrict__ Qb,   // [4*4096, 1536]
    const unsigned short* __restrict__ Kb,   // [640, 1536]; rows c*154+e
    const unsigned short* __restrict__ Vt,   // [4][24][64][160]
    const float* __restrict__ temp,
    unsigned short* __restrict__ Ob) {       // [4*4096, 1536]
  __shared__ unsigned short P[4][4][16][160];  // [wave][c][s][e] bf16 weights
  const int h = blockIdx.y, sb = blockIdx.x;
  const int t = threadIdx.x, w = t >> 6, l = t & 63, lr = l & 15, lg = l >> 4;
  const int s0 = sb * 64 + w * 16;
  const float sc = 1.0f / (temp[0] + 1e-8f);

  // Q B-fragments (held in registers all kernel): lane holds s=lr, 8 consecutive d
  short8 qf[4][2];
#pragma unroll
  for (int c = 0; c < 4; ++c)
#pragma unroll
    for (int kt = 0; kt < 2; ++kt)
      qf[c][kt] = *(const short8*)(Qb + (long)(c * 4096 + s0 + lr) * 1536 + h * 64 + kt * 32 + lg * 8);

  // ---- scores (S^T = K * Q^T so lane holds fixed s, e varies over regs) + softmax over c ----
  for (int et = 0; et < 10; ++et) {
    f32x4 sa[4] = {};
#pragma unroll
    for (int c = 0; c < 4; ++c)
#pragma unroll
      for (int kt = 0; kt < 2; ++kt) {
        short8 kf = *(const short8*)(Kb + (long)(c * 154 + et * 16 + lr) * 1536 + h * 64 + kt * 32 + lg * 8);
        sa[c] = __builtin_amdgcn_mfma_f32_16x16x32_bf16(kf, qf[c][kt], sa[c], 0, 0, 0);
      }
    float wv[4][4];
#pragma unroll
    for (int r = 0; r < 4; ++r) {
      float x0 = sa[0][r] * sc, x1 = sa[1][r] * sc, x2 = sa[2][r] * sc, x3 = sa[3][r] * sc;
      float m = fmaxf(fmaxf(x0, x1), fmaxf(x2, x3));
      float e0 = __expf(x0 - m), e1 = __expf(x1 - m), e2 = __expf(x2 - m), e3 = __expf(x3 - m);
      float inv = 1.0f / (e0 + e1 + e2 + e3);
      wv[0][r] = e0 * inv; wv[1][r] = e1 * inv; wv[2][r] = e2 * inv; wv[3][r] = e3 * inv;
    }
#pragma unroll
    for (int c = 0; c < 4; ++c) {
      us4 pk;
      pk[0] = f2bf(wv[c][0]); pk[1] = f2bf(wv[c][1]); pk[2] = f2bf(wv[c][2]); pk[3] = f2bf(wv[c][3]);
      *(us4*)&P[w][c][lr][et * 16 + lg * 4] = pk;  // e = et*16 + lg*4 + r
    }
  }
  __syncthreads();

  // ---- PV: out[s,d] = sum_e P[s,e] * V[e,d]; V fragments read straight from L2-resident Vt ----
  f32x4 o[4][4] = {};
#pragma unroll
  for (int c = 0; c < 4; ++c)
    for (int ks = 0; ks < 5; ++ks) {
      short8 pf = *(const short8*)&P[w][c][lr][ks * 32 + lg * 8];
#pragma unroll
      for (int nt = 0; nt < 4; ++nt) {
        short8 vf = *(const short8*)(Vt + (long)((c * 24 + h) * 64 + nt * 16 + lr) * 160 + ks * 32 + lg * 8);
        o[c][nt] = __builtin_amdgcn_mfma_f32_16x16x32_bf16(pf, vf, o[c][nt], 0, 0, 0);
      }
    }

#pragma unroll
  for (int c = 0; c < 4; ++c)
#pragma unroll
    for (int nt = 0; nt < 4; ++nt)
#pragma unroll
      for (int r = 0; r < 4; ++r)
        Ob[(long)(c * 4096 + s0 + lg * 4 + r) * 1536 + h * 64 + nt * 16 + lr] = f2bf(o[c][nt][r]);
}

extern "C" void kernel_launch(void* const* d_in, const int* in_sizes, int n_in,
                              void* d_out, int out_size, void* d_ws, size_t ws_size,
                              hipStream_t stream) {
  (void)in_sizes; (void)n_in; (void)out_size; (void)ws_size;
  const float* HS  = (const float*)d_in[0];
  const float* EHS = (const float*)d_in[1];
  const float* TMP = (const float*)d_in[2];
  const float* Wq  = (const float*)d_in[3];
  const float* Wk  = (const float*)d_in[4];
  const float* Wv  = (const float*)d_in[5];
  const float* Wo  = (const float*)d_in[6];
  const float* bo  = (const float*)d_in[7];

  char* ws = (char*)d_ws;
  size_t off = 0;
  unsigned short* HSb  = (unsigned short*)(ws + off); off += (size_t)16384 * 1536 * 2;  // reused as Ob
  unsigned short* Ob   = HSb;
  unsigned short* EHSb = (unsigned short*)(ws + off); off += (size_t)616 * 1536 * 2;
  unsigned short* Wqb  = (unsigned short*)(ws + off); off += (size_t)1536 * 1536 * 2;
  unsigned short* Wkb  = (unsigned short*)(ws + off); off += (size_t)1536 * 1536 * 2;
  unsigned short* Wvb  = (unsigned short*)(ws + off); off += (size_t)1536 * 1536 * 2;
  unsigned short* Wob  = (unsigned short*)(ws + off); off += (size_t)1536 * 1536 * 2;
  unsigned short* Kb   = (unsigned short*)(ws + off); off += (size_t)640 * 1536 * 2;
  unsigned short* Vb   = (unsigned short*)(ws + off); off += (size_t)640 * 1536 * 2;
  unsigned short* Vt   = (unsigned short*)(ws + off); off += (size_t)4 * 24 * 64 * 160 * 2;
  unsigned short* Qb   = (unsigned short*)d_out;  // bf16 scratch; final GEMM overwrites d_out fully

  cvt_kernel<<<2048, 256, 0, stream>>>(HS,  HSb,  16384 * 1536 / 4);
  cvt_kernel<<<512,  256, 0, stream>>>(EHS, EHSb, 616 * 1536 / 4);
  cvt_kernel<<<512,  256, 0, stream>>>(Wq,  Wqb,  1536 * 1536 / 4);
  cvt_kernel<<<512,  256, 0, stream>>>(Wk,  Wkb,  1536 * 1536 / 4);
  cvt_kernel<<<512,  256, 0, stream>>>(Wv,  Wvb,  1536 * 1536 / 4);
  cvt_kernel<<<512,  256, 0, stream>>>(Wo,  Wob,  1536 * 1536 / 4);

  gemm_bt<0><<<dim3(128, 12), 256, 0, stream>>>(HSb,  Wqb, Qb, nullptr, nullptr, nullptr, 1536, 1536, 16383);
  gemm_bt<0><<<dim3(5, 12),   256, 0, stream>>>(EHSb, Wkb, Kb, nullptr, nullptr, nullptr, 1536, 1536, 615);
  gemm_bt<0><<<dim3(5, 12),   256, 0, stream>>>(EHSb, Wvb, Vb, nullptr, nullptr, nullptr, 1536, 1536, 615);

  vtrans<<<96, 256, 0, stream>>>(Vb, Vt);

  attn_kernel<<<dim3(64, 24), 256, 0, stream>>>(Qb, Kb, Vt, TMP, Ob);

  gemm_bt<1><<<dim3(128, 12), 256, 0, stream>>>(Ob, Wob, nullptr, (float*)d_out, bo, HS, 1536, 1536, 16383);
}

// Round 2
// 420.156 us; speedup vs baseline: 1.1448x; 1.1448x over previous
//
#include <hip/hip_runtime.h>

typedef __attribute__((ext_vector_type(8))) short short8;
typedef __attribute__((ext_vector_type(4))) float f32x4;
typedef __attribute__((ext_vector_type(4))) unsigned short us4;
typedef __attribute__((ext_vector_type(4))) float float4v;

#define GLB_PTR(p) ((const __attribute__((address_space(1))) void*)(p))
#define LDS_PTR(p) ((__attribute__((address_space(3))) void*)(p))

__device__ __forceinline__ unsigned short f2bf(float f) {
  unsigned int u = __float_as_uint(f);
  u += 0x7FFF + ((u >> 16) & 1);   // round-to-nearest-even
  return (unsigned short)(u >> 16);
}

// ---------------- fp32 -> bf16 convert (vectorized) ----------------
__global__ void cvt_kernel(const float* __restrict__ in, unsigned short* __restrict__ out, int n4) {
  int i = blockIdx.x * blockDim.x + threadIdx.x;
  int stride = gridDim.x * blockDim.x;
  for (; i < n4; i += stride) {
    float4v v = *(const float4v*)(in + (size_t)i * 4);
    us4 o;
    o[0] = f2bf(v[0]); o[1] = f2bf(v[1]); o[2] = f2bf(v[2]); o[3] = f2bf(v[3]);
    *(us4*)(out + (size_t)i * 4) = o;
  }
}

// 4 weight matrices in one launch (blockIdx.y selects tensor)
__global__ void cvt4_kernel(const float* __restrict__ w0, const float* __restrict__ w1,
                            const float* __restrict__ w2, const float* __restrict__ w3,
                            unsigned short* __restrict__ o0, unsigned short* __restrict__ o1,
                            unsigned short* __restrict__ o2, unsigned short* __restrict__ o3,
                            int n4) {
  const float* in = blockIdx.y == 0 ? w0 : blockIdx.y == 1 ? w1 : blockIdx.y == 2 ? w2 : w3;
  unsigned short* out = blockIdx.y == 0 ? o0 : blockIdx.y == 1 ? o1 : blockIdx.y == 2 ? o2 : o3;
  int i = blockIdx.x * blockDim.x + threadIdx.x;
  int stride = gridDim.x * blockDim.x;
  for (; i < n4; i += stride) {
    float4v v = *(const float4v*)(in + (size_t)i * 4);
    us4 o;
    o[0] = f2bf(v[0]); o[1] = f2bf(v[1]); o[2] = f2bf(v[2]); o[3] = f2bf(v[3]);
    *(us4*)(out + (size_t)i * 4) = o;
  }
}

// ---------------- big bf16 GEMM: C[16384,1536] = A[16384,1536] * B[1536,1536]^T ----------------
// 256x128 block tile, BK=32, 4 waves (2Mx2N), wave tile 128x64 (8x4 fragments).
// Double-buffered LDS, 2-phase pipeline (stage next tile before compute, one barrier/tile).
// XOR granule swizzle (pre-swizzled global source + swizzled ds_read).
// MODE 0: C bf16.  MODE 1: C fp32 = acc + bias[n] + resid[m,n].
template<int MODE>
__global__ __launch_bounds__(256, 2) void gemm_big(
    const unsigned short* __restrict__ A,
    const unsigned short* __restrict__ B,
    unsigned short* __restrict__ Cb,
    float* __restrict__ Cf,
    const float* __restrict__ bias,
    const float* __restrict__ resid) {
  constexpr int K = 1536, N = 1536, BK = 32, NKT = K / BK;  // 48 K-tiles
  __shared__ unsigned short As[2][256 * 32];
  __shared__ unsigned short Bs[2][128 * 32];

  // XCD-chunked swizzle: 768 blocks -> 96/XCD = 8 m-tiles x 12 n-tiles, n fastest
  const int bid = blockIdx.x;
  const int xcd = bid & 7, idx = bid >> 3;
  const int m0 = (xcd * 8 + idx / 12) * 256;
  const int n0 = (idx % 12) * 128;

  const int t = threadIdx.x;
  const int w = t >> 6, l = t & 63, lr = l & 15, lg = l >> 4;
  const int wr = w >> 1, wc = w & 1;
  const int ga = lg ^ (lr & 3);                    // swizzled read granule (per-thread const)

  // staging source: thread t -> LDS byte t*16 (linear); row = t/4, granule swizzled by row&3
  const int srow = t >> 2;
  const int sg = (t & 3) ^ (srow & 3);
  const unsigned short* aSrc = A + (size_t)(m0 + srow) * K + sg * 8;
  const unsigned short* bSrc = B + (size_t)(n0 + srow) * K + sg * 8;

  f32x4 acc[8][4] = {};

  auto stage = [&](int buf, int k0) {
    unsigned short* AsW = &As[buf][0] + w * 512;   // wave-uniform base (w*1024 bytes)
    unsigned short* BsW = &Bs[buf][0] + w * 512;
#pragma unroll
    for (int i = 0; i < 4; ++i)
      __builtin_amdgcn_global_load_lds(GLB_PTR(aSrc + (size_t)(i * 64) * K + k0), LDS_PTR(AsW + i * 2048), 16, 0, 0);
#pragma unroll
    for (int i = 0; i < 2; ++i)
      __builtin_amdgcn_global_load_lds(GLB_PTR(bSrc + (size_t)(i * 64) * K + k0), LDS_PTR(BsW + i * 2048), 16, 0, 0);
  };

  auto compute = [&](const unsigned short* Asb, const unsigned short* Bsb) {
    short8 af[8], bfv[4];
#pragma unroll
    for (int i = 0; i < 8; ++i)
      af[i] = *(const short8*)(Asb + (wr * 128 + i * 16 + lr) * 32 + ga * 8);
#pragma unroll
    for (int j = 0; j < 4; ++j)
      bfv[j] = *(const short8*)(Bsb + (wc * 64 + j * 16 + lr) * 32 + ga * 8);
#pragma unroll
    for (int i = 0; i < 8; ++i)
#pragma unroll
      for (int j = 0; j < 4; ++j)
        acc[i][j] = __builtin_amdgcn_mfma_f32_16x16x32_bf16(af[i], bfv[j], acc[i][j], 0, 0, 0);
  };

  stage(0, 0);
  __syncthreads();
  for (int kt = 0; kt < NKT; kt += 2) {
    if (kt + 1 < NKT) stage(1, (kt + 1) * BK);
    compute(&As[0][0], &Bs[0][0]);
    __syncthreads();                                // drains stage(1) + lgkm
    if (kt + 2 < NKT) stage(0, (kt + 2) * BK);
    compute(&As[1][0], &Bs[1][0]);
    __syncthreads();                                // drains stage(0) + lgkm
  }

#pragma unroll
  for (int i = 0; i < 8; ++i) {
    const int rb = m0 + wr * 128 + i * 16 + lg * 4;
#pragma unroll
    for (int j = 0; j < 4; ++j) {
      const int col = n0 + wc * 64 + j * 16 + lr;
#pragma unroll
      for (int r = 0; r < 4; ++r) {
        size_t o = (size_t)(rb + r) * N + col;
        if (MODE == 0) Cb[o] = f2bf(acc[i][j][r]);
        else           Cf[o] = acc[i][j][r] + bias[col] + resid[o];
      }
    }
  }
}

// ---------------- K+V projection (small M): 128x128 tile, merged into one launch ----------------
__global__ __launch_bounds__(256) void gemm_kv(
    const unsigned short* __restrict__ A,    // EHSb [616,1536]
    const unsigned short* __restrict__ Bk,
    const unsigned short* __restrict__ Bv,
    unsigned short* __restrict__ Ck,
    unsigned short* __restrict__ Cv) {
  constexpr int K = 1536, N = 1536, Mc = 615;
  __shared__ unsigned short As[128 * 32];
  __shared__ unsigned short Bs[128 * 32];
  const unsigned short* B = blockIdx.y < 12 ? Bk : Bv;
  unsigned short* C = blockIdx.y < 12 ? Ck : Cv;
  const int m0 = blockIdx.x * 128, n0 = (blockIdx.y % 12) * 128;
  const int t = threadIdx.x;
  const int w = t >> 6, l = t & 63, lr = l & 15, lg = l >> 4;
  const int wr = w >> 1, wc = w & 1;
  const int srow = t >> 2, scol = (t & 3) * 8;

  f32x4 acc[4][4] = {};
  unsigned short* AsW = As + w * 512;
  unsigned short* BsW = Bs + w * 512;
  long ar0 = m0 + srow;       if (ar0 > Mc) ar0 = Mc;
  long ar1 = m0 + srow + 64;  if (ar1 > Mc) ar1 = Mc;

  for (int k0 = 0; k0 < K; k0 += 32) {
    __builtin_amdgcn_global_load_lds(GLB_PTR(A + ar0 * (long)K + k0 + scol), LDS_PTR(AsW),        16, 0, 0);
    __builtin_amdgcn_global_load_lds(GLB_PTR(A + ar1 * (long)K + k0 + scol), LDS_PTR(AsW + 2048), 16, 0, 0);
    __builtin_amdgcn_global_load_lds(GLB_PTR(B + (long)(n0 + srow) * K + k0 + scol),      LDS_PTR(BsW),        16, 0, 0);
    __builtin_amdgcn_global_load_lds(GLB_PTR(B + (long)(n0 + srow + 64) * K + k0 + scol), LDS_PTR(BsW + 2048), 16, 0, 0);
    __syncthreads();

    short8 af[4], bfv[4];
#pragma unroll
    for (int i = 0; i < 4; ++i) {
      af[i]  = *(const short8*)(As + (wr * 64 + i * 16 + lr) * 32 + lg * 8);
      bfv[i] = *(const short8*)(Bs + (wc * 64 + i * 16 + lr) * 32 + lg * 8);
    }
#pragma unroll
    for (int i = 0; i < 4; ++i)
#pragma unroll
      for (int j = 0; j < 4; ++j)
        acc[i][j] = __builtin_amdgcn_mfma_f32_16x16x32_bf16(af[i], bfv[j], acc[i][j], 0, 0, 0);
    __syncthreads();
  }

#pragma unroll
  for (int i = 0; i < 4; ++i) {
    int rb = m0 + wr * 64 + i * 16 + lg * 4;
#pragma unroll
    for (int j = 0; j < 4; ++j) {
      int col = n0 + wc * 64 + j * 16 + lr;
#pragma unroll
      for (int r = 0; r < 4; ++r)
        C[(long)(rb + r) * N + col] = f2bf(acc[i][j][r]);
    }
  }
}

// ---------------- V transpose: Vb[(c*154+e), h*64+d] -> Vt[c][h][d][e(160, zero-pad)] ----------------
__global__ void vtrans(const unsigned short* __restrict__ Vb, unsigned short* __restrict__ Vt) {
  int c = blockIdx.x / 24, h = blockIdx.x % 24;
  for (int idx = threadIdx.x; idx < 64 * 160; idx += blockDim.x) {
    int d = idx & 63, e = idx >> 6;
    unsigned short v = 0;
    if (e < 154) v = Vb[(long)(c * 154 + e) * 1536 + h * 64 + d];
    Vt[((long)((c * 24 + h) * 64 + d)) * 160 + e] = v;
  }
}

// ---------------- fused cross-component attention ----------------
__global__ __launch_bounds__(256) void attn_kernel(
    const unsigned short* __restrict__ Qb,   // [4*4096, 1536]
    const unsigned short* __restrict__ Kb,   // [640, 1536]; rows c*154+e
    const unsigned short* __restrict__ Vt,   // [4][24][64][160]
    const float* __restrict__ temp,
    unsigned short* __restrict__ Ob) {       // [4*4096, 1536]
  __shared__ unsigned short P[4][4][16][160];  // [wave][c][s][e] bf16 weights
  const int h = blockIdx.y, sb = blockIdx.x;
  const int t = threadIdx.x, w = t >> 6, l = t & 63, lr = l & 15, lg = l >> 4;
  const int s0 = sb * 64 + w * 16;
  const float sc = 1.0f / (temp[0] + 1e-8f);

  short8 qf[4][2];
#pragma unroll
  for (int c = 0; c < 4; ++c)
#pragma unroll
    for (int kt = 0; kt < 2; ++kt)
      qf[c][kt] = *(const short8*)(Qb + (long)(c * 4096 + s0 + lr) * 1536 + h * 64 + kt * 32 + lg * 8);

  for (int et = 0; et < 10; ++et) {
    f32x4 sa[4] = {};
#pragma unroll
    for (int c = 0; c < 4; ++c)
#pragma unroll
      for (int kt = 0; kt < 2; ++kt) {
        short8 kf = *(const short8*)(Kb + (long)(c * 154 + et * 16 + lr) * 1536 + h * 64 + kt * 32 + lg * 8);
        sa[c] = __builtin_amdgcn_mfma_f32_16x16x32_bf16(kf, qf[c][kt], sa[c], 0, 0, 0);
      }
    float wv[4][4];
#pragma unroll
    for (int r = 0; r < 4; ++r) {
      float x0 = sa[0][r] * sc, x1 = sa[1][r] * sc, x2 = sa[2][r] * sc, x3 = sa[3][r] * sc;
      float m = fmaxf(fmaxf(x0, x1), fmaxf(x2, x3));
      float e0 = __expf(x0 - m), e1 = __expf(x1 - m), e2 = __expf(x2 - m), e3 = __expf(x3 - m);
      float inv = 1.0f / (e0 + e1 + e2 + e3);
      wv[0][r] = e0 * inv; wv[1][r] = e1 * inv; wv[2][r] = e2 * inv; wv[3][r] = e3 * inv;
    }
#pragma unroll
    for (int c = 0; c < 4; ++c) {
      us4 pk;
      pk[0] = f2bf(wv[c][0]); pk[1] = f2bf(wv[c][1]); pk[2] = f2bf(wv[c][2]); pk[3] = f2bf(wv[c][3]);
      *(us4*)&P[w][c][lr][et * 16 + lg * 4] = pk;
    }
  }
  __syncthreads();

  f32x4 o[4][4] = {};
#pragma unroll
  for (int c = 0; c < 4; ++c)
    for (int ks = 0; ks < 5; ++ks) {
      short8 pf = *(const short8*)&P[w][c][lr][ks * 32 + lg * 8];
#pragma unroll
      for (int nt = 0; nt < 4; ++nt) {
        short8 vf = *(const short8*)(Vt + (long)((c * 24 + h) * 64 + nt * 16 + lr) * 160 + ks * 32 + lg * 8);
        o[c][nt] = __builtin_amdgcn_mfma_f32_16x16x32_bf16(pf, vf, o[c][nt], 0, 0, 0);
      }
    }

#pragma unroll
  for (int c = 0; c < 4; ++c)
#pragma unroll
    for (int nt = 0; nt < 4; ++nt)
#pragma unroll
      for (int r = 0; r < 4; ++r)
        Ob[(long)(c * 4096 + s0 + lg * 4 + r) * 1536 + h * 64 + nt * 16 + lr] = f2bf(o[c][nt][r]);
}

extern "C" void kernel_launch(void* const* d_in, const int* in_sizes, int n_in,
                              void* d_out, int out_size, void* d_ws, size_t ws_size,
                              hipStream_t stream) {
  (void)in_sizes; (void)n_in; (void)out_size; (void)ws_size;
  const float* HS  = (const float*)d_in[0];
  const float* EHS = (const float*)d_in[1];
  const float* TMP = (const float*)d_in[2];
  const float* Wq  = (const float*)d_in[3];
  const float* Wk  = (const float*)d_in[4];
  const float* Wv  = (const float*)d_in[5];
  const float* Wo  = (const float*)d_in[6];
  const float* bo  = (const float*)d_in[7];

  char* ws = (char*)d_ws;
  size_t off = 0;
  unsigned short* HSb  = (unsigned short*)(ws + off); off += (size_t)16384 * 1536 * 2;  // reused as Ob
  unsigned short* Ob   = HSb;
  unsigned short* EHSb = (unsigned short*)(ws + off); off += (size_t)616 * 1536 * 2;
  unsigned short* Wqb  = (unsigned short*)(ws + off); off += (size_t)1536 * 1536 * 2;
  unsigned short* Wkb  = (unsigned short*)(ws + off); off += (size_t)1536 * 1536 * 2;
  unsigned short* Wvb  = (unsigned short*)(ws + off); off += (size_t)1536 * 1536 * 2;
  unsigned short* Wob  = (unsigned short*)(ws + off); off += (size_t)1536 * 1536 * 2;
  unsigned short* Kb   = (unsigned short*)(ws + off); off += (size_t)640 * 1536 * 2;
  unsigned short* Vb   = (unsigned short*)(ws + off); off += (size_t)640 * 1536 * 2;
  unsigned short* Vt   = (unsigned short*)(ws + off); off += (size_t)4 * 24 * 64 * 160 * 2;
  unsigned short* Qb   = (unsigned short*)d_out;  // bf16 scratch; final GEMM overwrites d_out fully

  cvt_kernel<<<2048, 256, 0, stream>>>(HS,  HSb,  16384 * 1536 / 4);
  cvt_kernel<<<512,  256, 0, stream>>>(EHS, EHSb, 616 * 1536 / 4);
  cvt4_kernel<<<dim3(576, 4), 256, 0, stream>>>(Wq, Wk, Wv, Wo, Wqb, Wkb, Wvb, Wob, 1536 * 1536 / 4);

  gemm_big<0><<<768, 256, 0, stream>>>(HSb, Wqb, Qb, nullptr, nullptr, nullptr);
  gemm_kv<<<dim3(5, 24), 256, 0, stream>>>(EHSb, Wkb, Wvb, Kb, Vb);

  vtrans<<<96, 256, 0, stream>>>(Vb, Vt);

  attn_kernel<<<dim3(64, 24), 256, 0, stream>>>(Qb, Kb, Vt, TMP, Ob);

  gemm_big<1><<<768, 256, 0, stream>>>(Ob, Wob, nullptr, (float*)d_out, bo, HS);
}

// Round 3
// 404.065 us; speedup vs baseline: 1.1904x; 1.0398x over previous
//
#include <hip/hip_runtime.h>

typedef __attribute__((ext_vector_type(8))) short short8;
typedef __attribute__((ext_vector_type(4))) float f32x4;
typedef __attribute__((ext_vector_type(4))) unsigned short us4;
typedef __attribute__((ext_vector_type(4))) float float4v;

#define GLB_PTR(p) ((const __attribute__((address_space(1))) void*)(p))
#define LDS_PTR(p) ((__attribute__((address_space(3))) void*)(p))

__device__ __forceinline__ unsigned short f2bf(float f) {
  unsigned int u = __float_as_uint(f);
  u += 0x7FFF + ((u >> 16) & 1);   // round-to-nearest-even
  return (unsigned short)(u >> 16);
}

// ---------------- fp32 -> bf16 convert (vectorized) ----------------
__global__ void cvt_kernel(const float* __restrict__ in, unsigned short* __restrict__ out, int n4) {
  int i = blockIdx.x * blockDim.x + threadIdx.x;
  int stride = gridDim.x * blockDim.x;
  for (; i < n4; i += stride) {
    float4v v = *(const float4v*)(in + (size_t)i * 4);
    us4 o;
    o[0] = f2bf(v[0]); o[1] = f2bf(v[1]); o[2] = f2bf(v[2]); o[3] = f2bf(v[3]);
    *(us4*)(out + (size_t)i * 4) = o;
  }
}

// 4 weight matrices in one launch (blockIdx.y selects tensor)
__global__ void cvt4_kernel(const float* __restrict__ w0, const float* __restrict__ w1,
                            const float* __restrict__ w2, const float* __restrict__ w3,
                            unsigned short* __restrict__ o0, unsigned short* __restrict__ o1,
                            unsigned short* __restrict__ o2, unsigned short* __restrict__ o3,
                            int n4) {
  const float* in = blockIdx.y == 0 ? w0 : blockIdx.y == 1 ? w1 : blockIdx.y == 2 ? w2 : w3;
  unsigned short* out = blockIdx.y == 0 ? o0 : blockIdx.y == 1 ? o1 : blockIdx.y == 2 ? o2 : o3;
  int i = blockIdx.x * blockDim.x + threadIdx.x;
  int stride = gridDim.x * blockDim.x;
  for (; i < n4; i += stride) {
    float4v v = *(const float4v*)(in + (size_t)i * 4);
    us4 o;
    o[0] = f2bf(v[0]); o[1] = f2bf(v[1]); o[2] = f2bf(v[2]); o[3] = f2bf(v[3]);
    *(us4*)(out + (size_t)i * 4) = o;
  }
}

// ---------------- big bf16 GEMM: C[16384,1536] = A[16384,1536] * B[1536,1536]^T ----------------
// 256x128 block tile, BK=32, 4 waves (2Mx2N), wave tile 128x64 (8x4 fragments).
// Depth-3 pipeline, counted vmcnt (never 0 in steady state), raw s_barrier,
// setprio around MFMA cluster. XOR granule swizzle on LDS reads (pre-swizzled source).
// MODE 0: C bf16.  MODE 1: C fp32 = acc + bias[n] + resid[m,n].
template<int MODE>
__global__ __launch_bounds__(256, 2) void gemm_big(
    const unsigned short* __restrict__ A,
    const unsigned short* __restrict__ B,
    unsigned short* __restrict__ Cb,
    float* __restrict__ Cf,
    const float* __restrict__ bias,
    const float* __restrict__ resid) {
  constexpr int K = 1536, N = 1536, BK = 32, NKT = K / BK;  // 48 K-tiles
  __shared__ unsigned short As[3][256 * 32];
  __shared__ unsigned short Bs[3][128 * 32];

  // XCD-chunked swizzle: 768 blocks -> 96/XCD = 8 m-tiles x 12 n-tiles, n fastest
  const int bid = blockIdx.x;
  const int xcd = bid & 7, idx = bid >> 3;
  const int m0 = (xcd * 8 + idx / 12) * 256;
  const int n0 = (idx % 12) * 128;

  const int t = threadIdx.x;
  const int w = t >> 6, l = t & 63, lr = l & 15, lg = l >> 4;
  const int wr = w >> 1, wc = w & 1;
  const int ga = lg ^ (lr & 3);                    // swizzled read granule (per-thread const)

  // staging source: thread t -> LDS byte t*16 (linear); row = t/4, granule swizzled by row&3
  const int srow = t >> 2;
  const int sg = (t & 3) ^ (srow & 3);
  const unsigned short* aSrc = A + (size_t)(m0 + srow) * K + sg * 8;
  const unsigned short* bSrc = B + (size_t)(n0 + srow) * K + sg * 8;

  f32x4 acc[8][4] = {};

  auto stage = [&](int buf, int kt) {
    const int k0 = kt * BK;
    unsigned short* AsW = &As[buf][0] + w * 512;   // wave-uniform base (w*1024 bytes)
    unsigned short* BsW = &Bs[buf][0] + w * 512;
#pragma unroll
    for (int i = 0; i < 4; ++i)
      __builtin_amdgcn_global_load_lds(GLB_PTR(aSrc + (size_t)(i * 64) * K + k0), LDS_PTR(AsW + i * 2048), 16, 0, 0);
#pragma unroll
    for (int i = 0; i < 2; ++i)
      __builtin_amdgcn_global_load_lds(GLB_PTR(bSrc + (size_t)(i * 64) * K + k0), LDS_PTR(BsW + i * 2048), 16, 0, 0);
  };

  auto loadfrags = [&](int buf, short8* af, short8* bfv) {
    const unsigned short* Asb = &As[buf][0];
    const unsigned short* Bsb = &Bs[buf][0];
#pragma unroll
    for (int i = 0; i < 8; ++i)
      af[i] = *(const short8*)(Asb + (wr * 128 + i * 16 + lr) * 32 + ga * 8);
#pragma unroll
    for (int j = 0; j < 4; ++j)
      bfv[j] = *(const short8*)(Bsb + (wc * 64 + j * 16 + lr) * 32 + ga * 8);
  };

  auto mfma_all = [&](short8* af, short8* bfv) {
#pragma unroll
    for (int i = 0; i < 8; ++i)
#pragma unroll
      for (int j = 0; j < 4; ++j)
        acc[i][j] = __builtin_amdgcn_mfma_f32_16x16x32_bf16(af[i], bfv[j], acc[i][j], 0, 0, 0);
  };

  // prologue: 3 K-tiles in flight (18 loads/wave)
  stage(0, 0); stage(1, 1); stage(2, 2);

  int cur = 0;
  for (int kt = 0; kt < NKT - 3; ++kt) {
    asm volatile("s_waitcnt vmcnt(12)" ::: "memory");   // own 6 loads for buf cur retired
    __builtin_amdgcn_s_barrier();                       // all waves' cur-stage visible
    __builtin_amdgcn_sched_barrier(0);
    short8 af[8], bfv[4];
    loadfrags(cur, af, bfv);
    asm volatile("s_waitcnt lgkmcnt(0)" ::: "memory");  // frags in regs
    __builtin_amdgcn_sched_barrier(0);
    __builtin_amdgcn_s_barrier();                       // all waves done reading cur
    __builtin_amdgcn_sched_barrier(0);
    stage(cur, kt + 3);                                 // overwrite freed buffer
    __builtin_amdgcn_s_setprio(1);
    mfma_all(af, bfv);
    __builtin_amdgcn_s_setprio(0);
    cur = cur + 1; if (cur == 3) cur = 0;
  }
#pragma unroll
  for (int j = 0; j < 3; ++j) {                         // tail: drain 12 -> 6 -> 0
    if (j == 0)      asm volatile("s_waitcnt vmcnt(12)" ::: "memory");
    else if (j == 1) asm volatile("s_waitcnt vmcnt(6)" ::: "memory");
    else             asm volatile("s_waitcnt vmcnt(0)" ::: "memory");
    __builtin_amdgcn_s_barrier();
    __builtin_amdgcn_sched_barrier(0);
    short8 af[8], bfv[4];
    loadfrags(cur, af, bfv);
    mfma_all(af, bfv);
    cur = cur + 1; if (cur == 3) cur = 0;
  }

#pragma unroll
  for (int i = 0; i < 8; ++i) {
    const int rb = m0 + wr * 128 + i * 16 + lg * 4;
#pragma unroll
    for (int j = 0; j < 4; ++j) {
      const int col = n0 + wc * 64 + j * 16 + lr;
#pragma unroll
      for (int r = 0; r < 4; ++r) {
        size_t o = (size_t)(rb + r) * N + col;
        if (MODE == 0) Cb[o] = f2bf(acc[i][j][r]);
        else           Cf[o] = acc[i][j][r] + bias[col] + resid[o];
      }
    }
  }
}

// ---------------- K+V projection (small M): 128x128 tile, merged into one launch ----------------
__global__ __launch_bounds__(256) void gemm_kv(
    const unsigned short* __restrict__ A,    // EHSb [616,1536]
    const unsigned short* __restrict__ Bk,
    const unsigned short* __restrict__ Bv,
    unsigned short* __restrict__ Ck,
    unsigned short* __restrict__ Cv) {
  constexpr int K = 1536, N = 1536, Mc = 615;
  __shared__ unsigned short As[128 * 32];
  __shared__ unsigned short Bs[128 * 32];
  const unsigned short* B = blockIdx.y < 12 ? Bk : Bv;
  unsigned short* C = blockIdx.y < 12 ? Ck : Cv;
  const int m0 = blockIdx.x * 128, n0 = (blockIdx.y % 12) * 128;
  const int t = threadIdx.x;
  const int w = t >> 6, l = t & 63, lr = l & 15, lg = l >> 4;
  const int wr = w >> 1, wc = w & 1;
  const int srow = t >> 2, scol = (t & 3) * 8;

  f32x4 acc[4][4] = {};
  unsigned short* AsW = As + w * 512;
  unsigned short* BsW = Bs + w * 512;
  long ar0 = m0 + srow;       if (ar0 > Mc) ar0 = Mc;
  long ar1 = m0 + srow + 64;  if (ar1 > Mc) ar1 = Mc;

  for (int k0 = 0; k0 < K; k0 += 32) {
    __builtin_amdgcn_global_load_lds(GLB_PTR(A + ar0 * (long)K + k0 + scol), LDS_PTR(AsW),        16, 0, 0);
    __builtin_amdgcn_global_load_lds(GLB_PTR(A + ar1 * (long)K + k0 + scol), LDS_PTR(AsW + 2048), 16, 0, 0);
    __builtin_amdgcn_global_load_lds(GLB_PTR(B + (long)(n0 + srow) * K + k0 + scol),      LDS_PTR(BsW),        16, 0, 0);
    __builtin_amdgcn_global_load_lds(GLB_PTR(B + (long)(n0 + srow + 64) * K + k0 + scol), LDS_PTR(BsW + 2048), 16, 0, 0);
    __syncthreads();

    short8 af[4], bfv[4];
#pragma unroll
    for (int i = 0; i < 4; ++i) {
      af[i]  = *(const short8*)(As + (wr * 64 + i * 16 + lr) * 32 + lg * 8);
      bfv[i] = *(const short8*)(Bs + (wc * 64 + i * 16 + lr) * 32 + lg * 8);
    }
#pragma unroll
    for (int i = 0; i < 4; ++i)
#pragma unroll
      for (int j = 0; j < 4; ++j)
        acc[i][j] = __builtin_amdgcn_mfma_f32_16x16x32_bf16(af[i], bfv[j], acc[i][j], 0, 0, 0);
    __syncthreads();
  }

#pragma unroll
  for (int i = 0; i < 4; ++i) {
    int rb = m0 + wr * 64 + i * 16 + lg * 4;
#pragma unroll
    for (int j = 0; j < 4; ++j) {
      int col = n0 + wc * 64 + j * 16 + lr;
#pragma unroll
      for (int r = 0; r < 4; ++r)
        C[(long)(rb + r) * N + col] = f2bf(acc[i][j][r]);
    }
  }
}

// ---------------- V transpose: Vb[(c*154+e), h*64+d] -> Vt[c][h][d][e(160, zero-pad)] ----------------
__global__ void vtrans(const unsigned short* __restrict__ Vb, unsigned short* __restrict__ Vt) {
  int c = blockIdx.x / 24, h = blockIdx.x % 24;
  for (int idx = threadIdx.x; idx < 64 * 160; idx += blockDim.x) {
    int d = idx & 63, e = idx >> 6;
    unsigned short v = 0;
    if (e < 154) v = Vb[(long)(c * 154 + e) * 1536 + h * 64 + d];
    Vt[((long)((c * 24 + h) * 64 + d)) * 160 + e] = v;
  }
}

// ---------------- fused cross-component attention ----------------
__global__ __launch_bounds__(256) void attn_kernel(
    const unsigned short* __restrict__ Qb,   // [4*4096, 1536]
    const unsigned short* __restrict__ Kb,   // [640, 1536]; rows c*154+e
    const unsigned short* __restrict__ Vt,   // [4][24][64][160]
    const float* __restrict__ temp,
    unsigned short* __restrict__ Ob) {       // [4*4096, 1536]
  __shared__ unsigned short P[4][4][16][160];  // [wave][c][s][e] bf16 weights
  const int h = blockIdx.y, sb = blockIdx.x;
  const int t = threadIdx.x, w = t >> 6, l = t & 63, lr = l & 15, lg = l >> 4;
  const int s0 = sb * 64 + w * 16;
  const float sc = 1.0f / (temp[0] + 1e-8f);

  short8 qf[4][2];
#pragma unroll
  for (int c = 0; c < 4; ++c)
#pragma unroll
    for (int kt = 0; kt < 2; ++kt)
      qf[c][kt] = *(const short8*)(Qb + (long)(c * 4096 + s0 + lr) * 1536 + h * 64 + kt * 32 + lg * 8);

  for (int et = 0; et < 10; ++et) {
    f32x4 sa[4] = {};
#pragma unroll
    for (int c = 0; c < 4; ++c)
#pragma unroll
      for (int kt = 0; kt < 2; ++kt) {
        short8 kf = *(const short8*)(Kb + (long)(c * 154 + et * 16 + lr) * 1536 + h * 64 + kt * 32 + lg * 8);
        sa[c] = __builtin_amdgcn_mfma_f32_16x16x32_bf16(kf, qf[c][kt], sa[c], 0, 0, 0);
      }
    float wv[4][4];
#pragma unroll
    for (int r = 0; r < 4; ++r) {
      float x0 = sa[0][r] * sc, x1 = sa[1][r] * sc, x2 = sa[2][r] * sc, x3 = sa[3][r] * sc;
      float m = fmaxf(fmaxf(x0, x1), fmaxf(x2, x3));
      float e0 = __expf(x0 - m), e1 = __expf(x1 - m), e2 = __expf(x2 - m), e3 = __expf(x3 - m);
      float inv = 1.0f / (e0 + e1 + e2 + e3);
      wv[0][r] = e0 * inv; wv[1][r] = e1 * inv; wv[2][r] = e2 * inv; wv[3][r] = e3 * inv;
    }
#pragma unroll
    for (int c = 0; c < 4; ++c) {
      us4 pk;
      pk[0] = f2bf(wv[c][0]); pk[1] = f2bf(wv[c][1]); pk[2] = f2bf(wv[c][2]); pk[3] = f2bf(wv[c][3]);
      *(us4*)&P[w][c][lr][et * 16 + lg * 4] = pk;
    }
  }
  __syncthreads();

  f32x4 o[4][4] = {};
#pragma unroll
  for (int c = 0; c < 4; ++c)
    for (int ks = 0; ks < 5; ++ks) {
      short8 pf = *(const short8*)&P[w][c][lr][ks * 32 + lg * 8];
#pragma unroll
      for (int nt = 0; nt < 4; ++nt) {
        short8 vf = *(const short8*)(Vt + (long)((c * 24 + h) * 64 + nt * 16 + lr) * 160 + ks * 32 + lg * 8);
        o[c][nt] = __builtin_amdgcn_mfma_f32_16x16x32_bf16(pf, vf, o[c][nt], 0, 0, 0);
      }
    }

#pragma unroll
  for (int c = 0; c < 4; ++c)
#pragma unroll
    for (int nt = 0; nt < 4; ++nt)
#pragma unroll
      for (int r = 0; r < 4; ++r)
        Ob[(long)(c * 4096 + s0 + lg * 4 + r) * 1536 + h * 64 + nt * 16 + lr] = f2bf(o[c][nt][r]);
}

extern "C" void kernel_launch(void* const* d_in, const int* in_sizes, int n_in,
                              void* d_out, int out_size, void* d_ws, size_t ws_size,
                              hipStream_t stream) {
  (void)in_sizes; (void)n_in; (void)out_size; (void)ws_size;
  const float* HS  = (const float*)d_in[0];
  const float* EHS = (const float*)d_in[1];
  const float* TMP = (const float*)d_in[2];
  const float* Wq  = (const float*)d_in[3];
  const float* Wk  = (const float*)d_in[4];
  const float* Wv  = (const float*)d_in[5];
  const float* Wo  = (const float*)d_in[6];
  const float* bo  = (const float*)d_in[7];

  char* ws = (char*)d_ws;
  size_t off = 0;
  unsigned short* HSb  = (unsigned short*)(ws + off); off += (size_t)16384 * 1536 * 2;  // reused as Ob
  unsigned short* Ob   = HSb;
  unsigned short* EHSb = (unsigned short*)(ws + off); off += (size_t)616 * 1536 * 2;
  unsigned short* Wqb  = (unsigned short*)(ws + off); off += (size_t)1536 * 1536 * 2;
  unsigned short* Wkb  = (unsigned short*)(ws + off); off += (size_t)1536 * 1536 * 2;
  unsigned short* Wvb  = (unsigned short*)(ws + off); off += (size_t)1536 * 1536 * 2;
  unsigned short* Wob  = (unsigned short*)(ws + off); off += (size_t)1536 * 1536 * 2;
  unsigned short* Kb   = (unsigned short*)(ws + off); off += (size_t)640 * 1536 * 2;
  unsigned short* Vb   = (unsigned short*)(ws + off); off += (size_t)640 * 1536 * 2;
  unsigned short* Vt   = (unsigned short*)(ws + off); off += (size_t)4 * 24 * 64 * 160 * 2;
  unsigned short* Qb   = (unsigned short*)d_out;  // bf16 scratch; final GEMM overwrites d_out fully

  cvt_kernel<<<2048, 256, 0, stream>>>(HS,  HSb,  16384 * 1536 / 4);
  cvt_kernel<<<512,  256, 0, stream>>>(EHS, EHSb, 616 * 1536 / 4);
  cvt4_kernel<<<dim3(576, 4), 256, 0, stream>>>(Wq, Wk, Wv, Wo, Wqb, Wkb, Wvb, Wob, 1536 * 1536 / 4);

  gemm_big<0><<<768, 256, 0, stream>>>(HSb, Wqb, Qb, nullptr, nullptr, nullptr);
  gemm_kv<<<dim3(5, 24), 256, 0, stream>>>(EHSb, Wkb, Wvb, Kb, Vb);

  vtrans<<<96, 256, 0, stream>>>(Vb, Vt);

  attn_kernel<<<dim3(64, 24), 256, 0, stream>>>(Qb, Kb, Vt, TMP, Ob);

  gemm_big<1><<<768, 256, 0, stream>>>(Ob, Wob, nullptr, (float*)d_out, bo, HS);
}